// Round 1
// baseline (105.163 us; speedup 1.0000x reference)
//
#include <hip/hip_runtime.h>
#include <math.h>

// HardTripletLoss: B=4096, D=512, labels in [0,64), margin 0.5, scalar fp32 out.
// R5: = R4 (bf16 MFMA Gram, triangular blocks, double-buffered global_load_lds,
// 512-thread blocks) + XCD-aware block swizzle in k_dist (528 = 66*8, bijective
// chunked form). Primary goal this round: recover baseline rocprof counters.
//
// ws layout (floats): [0,4096)=hp, [4096,8192)=hn, [8192,12288)=norms,
//                     [12288,16384)=pad, [16384, +2M ushorts)=xhi (4 MB)

#define NB 4096
#define ND 512
#define NLAB 64

typedef __attribute__((ext_vector_type(8))) short short8;
typedef __attribute__((ext_vector_type(4))) float f32x4;

__device__ __forceinline__ ushort bf16rn(float f) {
    unsigned u = __float_as_uint(f);
    u += 0x7FFF + ((u >> 16) & 1);  // round-to-nearest-even
    return (ushort)(u >> 16);
}

__device__ __forceinline__ void gload_lds16(const ushort* g, ushort* l) {
    __builtin_amdgcn_global_load_lds(
        (const __attribute__((address_space(1))) void*)g,
        (__attribute__((address_space(3))) void*)l, 16, 0, 0);
}

// One wave per row: fp32->bf16 convert + exact fp32 norm; init hp/hn.
__global__ __launch_bounds__(256) void k_prep(const float* __restrict__ x,
                                              ushort* __restrict__ xhi,
                                              float* __restrict__ norms,
                                              float* __restrict__ hp,
                                              float* __restrict__ hn) {
    const int wave = threadIdx.x >> 6, lane = threadIdx.x & 63;
    const int row = blockIdx.x * 4 + wave;
    const float* p = x + (size_t)row * ND + lane * 8;
    float4 v0 = *(const float4*)p;
    float4 v1 = *(const float4*)(p + 4);
    ushort h[8];
    h[0] = bf16rn(v0.x); h[1] = bf16rn(v0.y); h[2] = bf16rn(v0.z); h[3] = bf16rn(v0.w);
    h[4] = bf16rn(v1.x); h[5] = bf16rn(v1.y); h[6] = bf16rn(v1.z); h[7] = bf16rn(v1.w);
    *(uint4*)(xhi + (size_t)row * ND + lane * 8) = *(const uint4*)h;
    float s = v0.x*v0.x + v0.y*v0.y + v0.z*v0.z + v0.w*v0.w
            + v1.x*v1.x + v1.y*v1.y + v1.z*v1.z + v1.w*v1.w;
    #pragma unroll
    for (int m = 1; m < 64; m <<= 1) s += __shfl_xor(s, m);
    if (lane == 0) norms[row] = s;
    if (threadIdx.x < 4) {
        hp[blockIdx.x * 4 + threadIdx.x] = 0.0f;
        hn[blockIdx.x * 4 + threadIdx.x] = __int_as_float(0x7F800000);
    }
}

// 128x128 tile, upper-triangle blocks (c>=r), 512 threads = 8 waves, each a
// 64x32 quadrant (4x2 tiles of mfma_f32_16x16x32_bf16). BK=64, double-buffered
// LDS with global_load_lds(16B); XOR chunk swizzle (phys = logical ^ (row&7))
// applied at the SOURCE address, un-applied at fragment reads -> 0 conflicts.
__global__ __launch_bounds__(512, 4) void k_dist(const ushort* __restrict__ xhi,
                                                 const int* __restrict__ labels,
                                                 const float* __restrict__ norms,
                                                 float* __restrict__ hp,
                                                 float* __restrict__ hn) {
    __shared__ ushort As0[128 * 64];  // 16 KB each; distinct arrays so the
    __shared__ ushort As1[128 * 64];  // compiler can disambiguate prefetch
    __shared__ ushort Bs0[128 * 64];  // writes from current-buffer ds_reads
    __shared__ ushort Bs1[128 * 64];

    // XCD-aware swizzle: 528 blocks = 66 * 8 XCDs exactly -> bijective chunked
    // remap. 66 consecutive triangular tiles (sharing A row-panels) per XCD L2.
    const int bid = (blockIdx.x & 7) * 66 + (blockIdx.x >> 3);

    // Triangular decode, closed form: bid -> (r, c), c >= r, 32x32 grid.
    int r = (int)((65.0f - sqrtf(4225.0f - 8.0f * (float)bid)) * 0.5f);
    int base = r * 32 - (r * (r - 1)) / 2;
    if (bid < base)                { --r; base = r * 32 - (r * (r - 1)) / 2; }
    else if (bid >= base + 32 - r) { ++r; base = r * 32 - (r * (r - 1)) / 2; }
    const int rb = r * 128;
    const int cb = (r + (bid - base)) * 128;

    const int tid = threadIdx.x;
    const int w = tid >> 6, lane = tid & 63;
    const int wr = (w >> 2) * 64;        // 2 row-quadrants
    const int wc = (w & 3) * 32;         // 4 col-quadrants
    const int q = lane >> 4, fr = lane & 15;

    f32x4 acc[4][2];
    #pragma unroll
    for (int mi = 0; mi < 4; ++mi)
        #pragma unroll
        for (int ni = 0; ni < 2; ++ni)
            acc[mi][ni] = (f32x4){0.f, 0.f, 0.f, 0.f};

    // Staging: waves 0-3 -> A tile, waves 4-7 -> B tile; wave covers rows
    // [(w&3)*32, +32) via 4 instrs of 8 rows each. Lane: row += L>>3,
    // phys chunk L&7, source logical chunk (L&7)^(row&7).
    const int srow8 = lane >> 3;
    const int sch = (lane & 7) ^ srow8;
    const int rgrp = (w & 3) * 32;
    const ushort* gbase = xhi + (size_t)(((w >> 2) ? cb : rb) + rgrp + srow8) * ND + sch * 8;
    const bool isB = (w >> 2) != 0;

    #define STAGE(At, Bt, kb)                                                  \
        {                                                                      \
            ushort* sb = (isB ? (Bt) : (At)) + rgrp * 64;                      \
            _Pragma("unroll")                                                  \
            for (int t = 0; t < 4; ++t)                                        \
                gload_lds16(gbase + (size_t)(t * 8) * ND + (kb), sb + t * 8 * 64); \
        }

    #define COMPUTE(At, Bt)                                                    \
        {                                                                      \
            _Pragma("unroll")                                                  \
            for (int kk = 0; kk < 2; ++kk) {                                   \
                short8 a[4], b[2];                                             \
                _Pragma("unroll")                                              \
                for (int mi = 0; mi < 4; ++mi) {                               \
                    const int R = wr + mi * 16 + fr;                           \
                    const int pc = ((kk << 2) | q) ^ (R & 7);                  \
                    a[mi] = *(const short8*)((At) + R * 64 + pc * 8);          \
                }                                                              \
                _Pragma("unroll")                                              \
                for (int ni = 0; ni < 2; ++ni) {                               \
                    const int R = wc + ni * 16 + fr;                           \
                    const int pc = ((kk << 2) | q) ^ (R & 7);                  \
                    b[ni] = *(const short8*)((Bt) + R * 64 + pc * 8);          \
                }                                                              \
                _Pragma("unroll")                                              \
                for (int mi = 0; mi < 4; ++mi)                                 \
                    _Pragma("unroll")                                          \
                    for (int ni = 0; ni < 2; ++ni)                             \
                        acc[mi][ni] = __builtin_amdgcn_mfma_f32_16x16x32_bf16( \
                            a[mi], b[ni], acc[mi][ni], 0, 0, 0);               \
            }                                                                  \
        }

    STAGE(As0, Bs0, 0)
    #pragma unroll
    for (int kb = 0; kb < 8; ++kb) {
        __syncthreads();  // drains this iter's buffer loads (issued 1 phase ago)
        if (kb & 1) {
            if (kb < 7) STAGE(As0, Bs0, (kb + 1) * 64)
            COMPUTE(As1, Bs1)
        } else {
            if (kb < 7) STAGE(As1, Bs1, (kb + 1) * 64)
            COMPUTE(As0, Bs0)
        }
    }

    // Epilogue. C/D layout: col = lane&15, row = (lane>>4)*4 + reg.
    int gcol[2]; float ncol[2]; int lcol[2];
    #pragma unroll
    for (int ni = 0; ni < 2; ++ni) {
        gcol[ni] = cb + wc + ni * 16 + fr;
        ncol[ni] = norms[gcol[ni]];
        lcol[ni] = labels[gcol[ni]];
    }
    float pmc[2], nmc[2];  // column-anchored stats
    #pragma unroll
    for (int ni = 0; ni < 2; ++ni) {
        pmc[ni] = 0.0f;
        nmc[ni] = __int_as_float(0x7F800000);
    }

    #pragma unroll
    for (int mi = 0; mi < 4; ++mi) {
        #pragma unroll
        for (int reg = 0; reg < 4; ++reg) {
            const int grow = rb + wr + mi * 16 + q * 4 + reg;
            const float nr = norms[grow];
            const int lr = labels[grow];
            float pm = 0.0f, nm = __int_as_float(0x7F800000);
            #pragma unroll
            for (int ni = 0; ni < 2; ++ni) {
                float sq = fmaxf(nr + ncol[ni] - 2.0f * acc[mi][ni][reg], 0.0f);
                float dd = sqrtf(sq);
                if (lr == lcol[ni]) {
                    if (grow != gcol[ni]) {
                        pm = fmaxf(pm, dd);
                        pmc[ni] = fmaxf(pmc[ni], dd);
                    }
                } else {
                    nm = fminf(nm, dd);
                    nmc[ni] = fminf(nmc[ni], dd);
                }
            }
            // row stats: reduce over the 16 column-lanes (lane bits 0..3)
            #pragma unroll
            for (int m = 1; m <= 8; m <<= 1) {
                pm = fmaxf(pm, __shfl_xor(pm, m));
                nm = fminf(nm, __shfl_xor(nm, m));
            }
            if (fr == 0) {
                atomicMax((int*)&hp[grow], __float_as_int(pm));
                atomicMin((int*)&hn[grow], __float_as_int(nm));
            }
        }
    }
    // col stats: reduce over the 4 quad-lanes (lane bits 4..5)
    #pragma unroll
    for (int ni = 0; ni < 2; ++ni) {
        #pragma unroll
        for (int m = 16; m <= 32; m <<= 1) {
            pmc[ni] = fmaxf(pmc[ni], __shfl_xor(pmc[ni], m));
            nmc[ni] = fminf(nmc[ni], __shfl_xor(nmc[ni], m));
        }
        if (q == 0) {
            atomicMax((int*)&hp[gcol[ni]], __float_as_int(pmc[ni]));
            atomicMin((int*)&hn[gcol[ni]], __float_as_int(nmc[ni]));
        }
    }
    #undef STAGE
    #undef COMPUTE
}

// Single block: label histogram in LDS, then validity + mean.
__global__ __launch_bounds__(1024) void k_finalize(const int* __restrict__ labels,
                                                   const float* __restrict__ hp,
                                                   const float* __restrict__ hn,
                                                   float* __restrict__ out) {
    __shared__ int h[NLAB];
    __shared__ float sw[16];
    __shared__ int cw[16];
    const int tid = threadIdx.x;
    if (tid < NLAB) h[tid] = 0;
    __syncthreads();
    for (int i = tid; i < NB; i += 1024) atomicAdd(&h[labels[i]], 1);
    __syncthreads();
    float s = 0.0f;
    int c = 0;
    for (int i = tid; i < NB; i += 1024) {
        const int k = h[labels[i]];
        if (k >= 2 && k < NB) {
            s += fmaxf(hp[i] - hn[i] + 0.5f, 0.0f);
            c += 1;
        }
    }
    #pragma unroll
    for (int m = 1; m < 64; m <<= 1) {
        s += __shfl_xor(s, m);
        c += __shfl_xor(c, m);
    }
    const int wave = tid >> 6, lane = tid & 63;
    if (lane == 0) { sw[wave] = s; cw[wave] = c; }
    __syncthreads();
    if (tid == 0) {
        float S = 0.0f; int C = 0;
        #pragma unroll
        for (int i = 0; i < 16; ++i) { S += sw[i]; C += cw[i]; }
        out[0] = (C > 0) ? (S / (float)C) : 0.0f;
    }
}

extern "C" void kernel_launch(void* const* d_in, const int* in_sizes, int n_in,
                              void* d_out, int out_size, void* d_ws, size_t ws_size,
                              hipStream_t stream) {
    const float* x      = (const float*)d_in[0];
    const int*   labels = (const int*)d_in[1];
    float* ws    = (float*)d_ws;
    float* hp    = ws;
    float* hn    = ws + NB;
    float* norms = ws + 2 * NB;
    ushort* xhi  = (ushort*)(ws + 4 * NB);   // 4 MB bf16 matrix
    float* out   = (float*)d_out;

    k_prep<<<dim3(NB / 4), dim3(256), 0, stream>>>(x, xhi, norms, hp, hn);
    k_dist<<<dim3(528), dim3(512), 0, stream>>>(xhi, labels, norms, hp, hn);
    k_finalize<<<dim3(1), dim3(1024), 0, stream>>>(labels, hp, hn, out);
}